// Round 1
// baseline (459.587 us; speedup 1.0000x reference)
//
#include <hip/hip_runtime.h>

#define A_N 120000
#define B_N 8
#define M_N 64

// ---------------------------------------------------------------------------
// Main kernel: one thread per (image, anchor).
// Computes IoU-max/argmax over 64 GT boxes (division-free via cross-mult),
// focal-loss and smooth-L1 contributions, wave-reduces, atomics into ws.
// ---------------------------------------------------------------------------
__global__ __launch_bounds__(256) void retina_main(
    const float* __restrict__ yt,       // (B, M, 5)  cx,cy,w,h,label
    const float* __restrict__ ycls,     // (B, A, 1)
    const float* __restrict__ yreg,     // (B, A, 4)
    const float* __restrict__ anchors,  // (A, 4)     x1,y1,x2,y2
    float* __restrict__ ws_f,           // [0..7] cls_sum, [8..15] reg_sum
    int*   __restrict__ ws_i)           // [0..7] num_pos
{
    __shared__ float4 s_box[M_N];   // gt corners (invalid -> degenerate far box)
    __shared__ float  s_area[M_N];  // gt area    (invalid -> 0)
    __shared__ float4 s_raw[M_N];   // raw cx,cy,w,h
    __shared__ float  s_lab[M_N];   // label

    const int b   = blockIdx.y;
    const int a   = blockIdx.x * 256 + threadIdx.x;
    const int tid = threadIdx.x;

    if (tid < M_N) {
        const float* g = yt + (b * M_N + tid) * 5;
        float cx = g[0], cy = g[1], w = g[2], h = g[3], lab = g[4];
        float x1 = cx - 0.5f * w, y1 = cy - 0.5f * h;
        float x2 = cx + 0.5f * w, y2 = cy + 0.5f * h;
        float ar = (x2 - x1) * (y2 - y1);
        if (lab == -1.0f) {         // invalid: degenerate far box -> inter=0, iou ratio 0
            x1 = y1 = x2 = y2 = 1e30f;
            ar = 0.0f;
        }
        s_box[tid]  = make_float4(x1, y1, x2, y2);
        s_area[tid] = ar;
        s_raw[tid]  = make_float4(cx, cy, w, h);
        s_lab[tid]  = lab;
    }
    __syncthreads();

    float clsv = 0.0f, regv = 0.0f;
    int   posi = 0;

    if (a < A_N) {
        float4 an = *reinterpret_cast<const float4*>(anchors + a * 4);
        const float aw  = an.z - an.x;
        const float ah  = an.w - an.y;
        const float acx = an.x + 0.5f * aw;
        const float acy = an.y + 0.5f * ah;
        const float area_a = aw * ah;

        // best iou tracked as fraction best_i / best_d (best_d > 0); init ratio = -1
        float best_i = -1.0f, best_d = 1.0f;
        int   arg = 0;
        #pragma unroll 8
        for (int g = 0; g < M_N; ++g) {
            float4 gb = s_box[g];
            float  ga = s_area[g];
            float w = fminf(an.z, gb.z) - fmaxf(an.x, gb.x);
            float h = fminf(an.w, gb.w) - fmaxf(an.y, gb.y);
            w = fmaxf(w, 0.0f);
            h = fmaxf(h, 0.0f);
            float inter = w * h;
            float denom = (area_a + ga) - inter;   // > 0 always
            // inter/denom > best_i/best_d  <=>  inter*best_d > best_i*denom
            if (inter * best_d > best_i * denom) { // strict > keeps FIRST max (JAX argmax)
                best_i = inter;
                best_d = denom;
                arg    = g;
            }
        }
        const bool pos = (best_i >= 0.5f * best_d);
        const bool neg = (best_i <  0.4f * best_d);
        posi = pos ? 1 : 0;

        const float p = ycls[(size_t)b * A_N + a];

        // target in {1, 0, -1}
        float target;
        if (pos) {
            int alab = (int)s_lab[arg];            // arg valid when pos
            target = (alab == 0) ? 1.0f : 0.0f;
        } else {
            target = neg ? 0.0f : -1.0f;
        }
        if (target == 1.0f) {
            float fw = 1.0f - p;
            clsv = 0.25f * fw * fw * (-logf(p));
        } else if (target == 0.0f) {
            clsv = 0.75f * p * p * (-logf(1.0f - p));
        }

        if (pos) {
            float4 ag = s_raw[arg];
            float gw = fmaxf(ag.z, 1.0f);
            float gh = fmaxf(ag.w, 1.0f);
            float t0 = ((ag.x - acx) / aw) / 0.1f;
            float t1 = ((ag.y - acy) / ah) / 0.1f;
            float t2 = logf(gw / aw) / 0.2f;
            float t3 = logf(gh / ah) / 0.2f;
            const float4 r = *reinterpret_cast<const float4*>(yreg + ((size_t)b * A_N + a) * 4);
            float d0 = fabsf(t0 - r.x);
            float d1 = fabsf(t1 - r.y);
            float d2 = fabsf(t2 - r.z);
            float d3 = fabsf(t3 - r.w);
            const float beta = 1.0f / 9.0f;
            const float hb   = 0.5f / 9.0f;
            regv  = (d0 <= beta) ? 4.5f * d0 * d0 : d0 - hb;
            regv += (d1 <= beta) ? 4.5f * d1 * d1 : d1 - hb;
            regv += (d2 <= beta) ? 4.5f * d2 * d2 : d2 - hb;
            regv += (d3 <= beta) ? 4.5f * d3 * d3 : d3 - hb;
        }
    }

    // wave (64-lane) reduction, then one atomic per wave
    for (int off = 32; off > 0; off >>= 1) {
        clsv += __shfl_down(clsv, off);
        regv += __shfl_down(regv, off);
    }
    unsigned long long pm = __ballot(posi);
    if ((tid & 63) == 0) {
        atomicAdd(&ws_f[b],        clsv);
        atomicAdd(&ws_f[B_N + b],  regv);
        atomicAdd(&ws_i[b],        (int)__popcll(pm));
    }
}

// ---------------------------------------------------------------------------
// Finalize: apply per-image num_pos normalization, mean over batch.
// ---------------------------------------------------------------------------
__global__ void retina_final(const float* __restrict__ ws_f,
                             const int*   __restrict__ ws_i,
                             float* __restrict__ out)
{
    int t = threadIdx.x;
    float c = 0.0f, r = 0.0f;
    if (t < B_N) {
        float np = (float)ws_i[t];
        c = ws_f[t] / fmaxf(np, 1.0f);
        r = (ws_i[t] > 0) ? ws_f[B_N + t] / fmaxf(np * 4.0f, 1.0f) : 0.0f;
    }
    for (int off = 4; off > 0; off >>= 1) {
        c += __shfl_down(c, off);
        r += __shfl_down(r, off);
    }
    if (t == 0) {
        out[0] = c * (1.0f / (float)B_N);
        out[1] = r * (1.0f / (float)B_N);
    }
}

extern "C" void kernel_launch(void* const* d_in, const int* in_sizes, int n_in,
                              void* d_out, int out_size, void* d_ws, size_t ws_size,
                              hipStream_t stream)
{
    const float* yt      = (const float*)d_in[0];  // y_true_tmp   (8,64,5)
    const float* ycls    = (const float*)d_in[1];  // y_classifs   (8,120000,1)
    const float* yreg    = (const float*)d_in[2];  // y_regressions(8,120000,4)
    const float* anchors = (const float*)d_in[3];  // anchors      (1,120000,4)

    float* ws_f = (float*)d_ws;
    int*   ws_i = (int*)((char*)d_ws + 2 * B_N * sizeof(float));

    // ws is re-poisoned to 0xAA before every launch — zero the accumulators
    hipMemsetAsync(d_ws, 0, 2 * B_N * sizeof(float) + B_N * sizeof(int), stream);

    dim3 grid((A_N + 255) / 256, B_N);
    retina_main<<<grid, 256, 0, stream>>>(yt, ycls, yreg, anchors, ws_f, ws_i);
    retina_final<<<1, 64, 0, stream>>>(ws_f, ws_i, (float*)d_out);
}

// Round 2
// 175.222 us; speedup vs baseline: 2.6229x; 2.6229x over previous
//
#include <hip/hip_runtime.h>

#define A_N 120000
#define B_N 8
#define M_N 64

// ---------------------------------------------------------------------------
// Main kernel: one thread per (image, anchor).
// IoU-max/argmax over 64 GT boxes (division-free via cross-mult, branchless),
// focal-loss and smooth-L1 contributions, block-reduces, 3 atomics per block.
// ---------------------------------------------------------------------------
__global__ __launch_bounds__(256, 2) void retina_main(
    const float* __restrict__ yt,       // (B, M, 5)  cx,cy,w,h,label
    const float* __restrict__ ycls,     // (B, A, 1)
    const float* __restrict__ yreg,     // (B, A, 4)
    const float* __restrict__ anchors,  // (A, 4)     x1,y1,x2,y2
    float* __restrict__ ws_f,           // [0..7] cls_sum, [8..15] reg_sum
    int*   __restrict__ ws_i)           // [0..7] num_pos
{
    __shared__ float4 s_box[M_N];   // gt corners (invalid -> degenerate far box)
    __shared__ float  s_area[M_N];  // gt area    (invalid -> 0)
    __shared__ float4 s_raw[M_N];   // raw cx,cy,w,h
    __shared__ float  s_lab[M_N];   // label
    __shared__ float  s_rc[4], s_rr[4];
    __shared__ int    s_rp[4];

    const int b   = blockIdx.y;
    const int a   = blockIdx.x * 256 + threadIdx.x;
    const int tid = threadIdx.x;

    if (tid < M_N) {
        const float* g = yt + (b * M_N + tid) * 5;
        float cx = g[0], cy = g[1], w = g[2], h = g[3], lab = g[4];
        float x1 = cx - 0.5f * w, y1 = cy - 0.5f * h;
        float x2 = cx + 0.5f * w, y2 = cy + 0.5f * h;
        float ar = (x2 - x1) * (y2 - y1);
        if (lab == -1.0f) {         // invalid: degenerate far box -> inter=0, ratio 0
            x1 = y1 = x2 = y2 = 1e30f;
            ar = 0.0f;
        }
        s_box[tid]  = make_float4(x1, y1, x2, y2);
        s_area[tid] = ar;
        s_raw[tid]  = make_float4(cx, cy, w, h);
        s_lab[tid]  = lab;
    }
    __syncthreads();

    float clsv = 0.0f, regv = 0.0f;
    int   posi = 0;

    if (a < A_N) {
        const float4 an = *reinterpret_cast<const float4*>(anchors + a * 4);
        // prefetch per-anchor globals before the loop (latency hidden under 64 iters)
        const float  p = ycls[(size_t)b * A_N + a];
        const float4 r = *reinterpret_cast<const float4*>(yreg + ((size_t)b * A_N + a) * 4);

        const float aw  = an.z - an.x;
        const float ah  = an.w - an.y;
        const float acx = an.x + 0.5f * aw;
        const float acy = an.y + 0.5f * ah;
        const float area_a = aw * ah;

        // best iou tracked as fraction best_i / best_d (best_d > 0); init ratio = -1
        float best_i = -1.0f, best_d = 1.0f;
        int   arg = 0;
        #pragma unroll 4
        for (int g = 0; g < M_N; ++g) {
            const float4 gb = s_box[g];
            const float  ga = s_area[g];
            float w = fminf(an.z, gb.z) - fmaxf(an.x, gb.x);
            float h = fminf(an.w, gb.w) - fmaxf(an.y, gb.y);
            float inter = fmaxf(w, 0.0f) * fmaxf(h, 0.0f);
            float denom = (area_a + ga) - inter;     // > 0 always
            // inter/denom > best_i/best_d  <=>  inter*best_d > best_i*denom
            // strict > keeps FIRST max (JAX argmax tie rule); branchless cndmask
            const bool better = inter * best_d > best_i * denom;
            best_i = better ? inter : best_i;
            best_d = better ? denom : best_d;
            arg    = better ? g     : arg;
        }
        const bool pos = (best_i >= 0.5f * best_d);
        const bool neg = (best_i <  0.4f * best_d);
        posi = pos ? 1 : 0;

        // target in {1, 0, -1}
        float target;
        if (pos) {
            int alab = (int)s_lab[arg];              // arg valid when pos
            target = (alab == 0) ? 1.0f : 0.0f;
        } else {
            target = neg ? 0.0f : -1.0f;
        }
        if (target == 1.0f) {
            float fw = 1.0f - p;
            clsv = 0.25f * fw * fw * (-logf(p));
        } else if (target == 0.0f) {
            clsv = 0.75f * p * p * (-logf(1.0f - p));
        }

        if (pos) {
            const float4 ag = s_raw[arg];
            float gw = fmaxf(ag.z, 1.0f);
            float gh = fmaxf(ag.w, 1.0f);
            float t0 = ((ag.x - acx) / aw) / 0.1f;
            float t1 = ((ag.y - acy) / ah) / 0.1f;
            float t2 = logf(gw / aw) / 0.2f;
            float t3 = logf(gh / ah) / 0.2f;
            float d0 = fabsf(t0 - r.x);
            float d1 = fabsf(t1 - r.y);
            float d2 = fabsf(t2 - r.z);
            float d3 = fabsf(t3 - r.w);
            const float beta = 1.0f / 9.0f;
            const float hb   = 0.5f / 9.0f;
            regv  = (d0 <= beta) ? 4.5f * d0 * d0 : d0 - hb;
            regv += (d1 <= beta) ? 4.5f * d1 * d1 : d1 - hb;
            regv += (d2 <= beta) ? 4.5f * d2 * d2 : d2 - hb;
            regv += (d3 <= beta) ? 4.5f * d3 * d3 : d3 - hb;
        }
    }

    // wave (64-lane) reduction
    for (int off = 32; off > 0; off >>= 1) {
        clsv += __shfl_down(clsv, off);
        regv += __shfl_down(regv, off);
    }
    const unsigned long long pm = __ballot(posi);
    const int wid = tid >> 6;
    if ((tid & 63) == 0) {
        s_rc[wid] = clsv;
        s_rr[wid] = regv;
        s_rp[wid] = (int)__popcll(pm);
    }
    __syncthreads();
    // one atomic set per block
    if (tid == 0) {
        float c  = s_rc[0] + s_rc[1] + s_rc[2] + s_rc[3];
        float rr = s_rr[0] + s_rr[1] + s_rr[2] + s_rr[3];
        int   pp = s_rp[0] + s_rp[1] + s_rp[2] + s_rp[3];
        atomicAdd(&ws_f[b],       c);
        atomicAdd(&ws_f[B_N + b], rr);
        atomicAdd(&ws_i[b],       pp);
    }
}

// ---------------------------------------------------------------------------
// Finalize: apply per-image num_pos normalization, mean over batch.
// ---------------------------------------------------------------------------
__global__ void retina_final(const float* __restrict__ ws_f,
                             const int*   __restrict__ ws_i,
                             float* __restrict__ out)
{
    int t = threadIdx.x;
    float c = 0.0f, r = 0.0f;
    if (t < B_N) {
        float np = (float)ws_i[t];
        c = ws_f[t] / fmaxf(np, 1.0f);
        r = (ws_i[t] > 0) ? ws_f[B_N + t] / fmaxf(np * 4.0f, 1.0f) : 0.0f;
    }
    for (int off = 4; off > 0; off >>= 1) {
        c += __shfl_down(c, off);
        r += __shfl_down(r, off);
    }
    if (t == 0) {
        out[0] = c * (1.0f / (float)B_N);
        out[1] = r * (1.0f / (float)B_N);
    }
}

extern "C" void kernel_launch(void* const* d_in, const int* in_sizes, int n_in,
                              void* d_out, int out_size, void* d_ws, size_t ws_size,
                              hipStream_t stream)
{
    const float* yt      = (const float*)d_in[0];  // y_true_tmp   (8,64,5)
    const float* ycls    = (const float*)d_in[1];  // y_classifs   (8,120000,1)
    const float* yreg    = (const float*)d_in[2];  // y_regressions(8,120000,4)
    const float* anchors = (const float*)d_in[3];  // anchors      (1,120000,4)

    float* ws_f = (float*)d_ws;
    int*   ws_i = (int*)((char*)d_ws + 2 * B_N * sizeof(float));

    // ws is re-poisoned to 0xAA before every launch — zero the accumulators
    hipMemsetAsync(d_ws, 0, 2 * B_N * sizeof(float) + B_N * sizeof(int), stream);

    dim3 grid((A_N + 255) / 256, B_N);
    retina_main<<<grid, 256, 0, stream>>>(yt, ycls, yreg, anchors, ws_f, ws_i);
    retina_final<<<1, 64, 0, stream>>>(ws_f, ws_i, (float*)d_out);
}

// Round 3
// 107.089 us; speedup vs baseline: 4.2916x; 1.6362x over previous
//
#include <hip/hip_runtime.h>

#define A_N 120000
#define B_N 8
#define M_N 64
#define APT 4                       // anchors per thread
#define TPB 256
#define GX  ((A_N + TPB*APT - 1) / (TPB*APT))   // 118 blocks in x

// ---------------------------------------------------------------------------
// Main kernel: each thread owns 4 anchors (strided by 256 for coalescing).
// IoU-max/argmax over 64 GT boxes, division-free, 4 independent dep chains.
// Per-block partial sums written to ws (no atomics, no memset needed).
// ---------------------------------------------------------------------------
__global__ __launch_bounds__(TPB, 4) void retina_main(
    const float* __restrict__ yt,       // (B, M, 5)  cx,cy,w,h,label
    const float* __restrict__ ycls,     // (B, A, 1)
    const float* __restrict__ yreg,     // (B, A, 4)
    const float* __restrict__ anchors,  // (A, 4)     x1,y1,x2,y2
    float* __restrict__ ws_cls,         // [B*GX] partial cls sums
    float* __restrict__ ws_reg,         // [B*GX] partial reg sums
    int*   __restrict__ ws_pos)         // [B*GX] partial pos counts
{
    __shared__ float4 s_box[M_N];   // gt corners (invalid -> degenerate far box)
    __shared__ float  s_area[M_N];  // gt area    (invalid -> 0)
    __shared__ float4 s_raw[M_N];   // raw cx,cy,w,h
    __shared__ float  s_lab[M_N];   // label
    __shared__ float  s_rc[4], s_rr[4];
    __shared__ int    s_rp[4];

    const int b   = blockIdx.y;
    const int tid = threadIdx.x;
    const int a0  = blockIdx.x * (TPB * APT) + tid;   // + k*TPB

    if (tid < M_N) {
        const float* g = yt + (b * M_N + tid) * 5;
        float cx = g[0], cy = g[1], w = g[2], h = g[3], lab = g[4];
        float x1 = cx - 0.5f * w, y1 = cy - 0.5f * h;
        float x2 = cx + 0.5f * w, y2 = cy + 0.5f * h;
        float ar = (x2 - x1) * (y2 - y1);
        if (lab == -1.0f) {         // invalid: degenerate far box -> inter=0, ratio 0
            x1 = y1 = x2 = y2 = 1e30f;
            ar = 0.0f;
        }
        s_box[tid]  = make_float4(x1, y1, x2, y2);
        s_area[tid] = ar;
        s_raw[tid]  = make_float4(cx, cy, w, h);
        s_lab[tid]  = lab;
    }
    __syncthreads();

    // ---- per-anchor state (static indices -> registers) ----
    float ax1[APT], ay1[APT], ax2[APT], ay2[APT], sa[APT], pp[APT];
    float bi[APT], bd[APT];
    int   ba[APT];
    bool  vld[APT];

    #pragma unroll
    for (int k = 0; k < APT; ++k) {
        int a = a0 + k * TPB;
        vld[k] = (a < A_N);
        int ac = vld[k] ? a : (A_N - 1);            // clamp, mask at tail
        float4 an = *reinterpret_cast<const float4*>(anchors + (size_t)ac * 4);
        ax1[k] = an.x; ay1[k] = an.y; ax2[k] = an.z; ay2[k] = an.w;
        sa[k]  = (an.z - an.x) * (an.w - an.y);     // anchor area
        pp[k]  = ycls[(size_t)b * A_N + ac];        // prefetch p
        bi[k] = -1.0f; bd[k] = 1.0f; ba[k] = 0;
    }

    // ---- inner loop over 64 GT boxes ----
    #pragma unroll 8
    for (int g = 0; g < M_N; ++g) {
        const float4 gb = s_box[g];
        const float  ga = s_area[g];
        #pragma unroll
        for (int k = 0; k < APT; ++k) {
            float w = fminf(ax2[k], gb.z) - fmaxf(ax1[k], gb.x);
            float h = fminf(ay2[k], gb.w) - fmaxf(ay1[k], gb.y);
            float inter = fmaxf(w, 0.0f) * fmaxf(h, 0.0f);
            float denom = (sa[k] + ga) - inter;     // > 0 always
            // inter/denom > bi/bd  <=>  inter*bd > bi*denom ; strict > = first-max
            bool better = inter * bd[k] > bi[k] * denom;
            bi[k] = better ? inter : bi[k];
            bd[k] = better ? denom : bd[k];
            ba[k] = better ? g     : ba[k];
        }
    }

    // ---- per-anchor tail: focal cls + smooth-L1 reg ----
    float clsv = 0.0f, regv = 0.0f;
    int   posn = 0;
    #pragma unroll
    for (int k = 0; k < APT; ++k) {
        if (!vld[k]) continue;
        const bool pos = (bi[k] >= 0.5f * bd[k]);
        const bool neg = (bi[k] <  0.4f * bd[k]);
        posn += pos ? 1 : 0;
        const float p = pp[k];

        float target;
        if (pos) {
            int alab = (int)s_lab[ba[k]];           // arg valid when pos
            target = (alab == 0) ? 1.0f : 0.0f;
        } else {
            target = neg ? 0.0f : -1.0f;
        }
        if (target == 1.0f) {
            float fw = 1.0f - p;
            clsv += 0.25f * fw * fw * (-logf(p));
        } else if (target == 0.0f) {
            clsv += 0.75f * p * p * (-logf(1.0f - p));
        }

        if (pos) {
            int a = a0 + k * TPB;
            const float aw  = ax2[k] - ax1[k];
            const float ah  = ay2[k] - ay1[k];
            const float acx = ax1[k] + 0.5f * aw;
            const float acy = ay1[k] + 0.5f * ah;
            const float4 ag = s_raw[ba[k]];
            const float4 r  = *reinterpret_cast<const float4*>(yreg + ((size_t)b * A_N + a) * 4);
            float gw = fmaxf(ag.z, 1.0f);
            float gh = fmaxf(ag.w, 1.0f);
            float t0 = ((ag.x - acx) / aw) / 0.1f;
            float t1 = ((ag.y - acy) / ah) / 0.1f;
            float t2 = logf(gw / aw) / 0.2f;
            float t3 = logf(gh / ah) / 0.2f;
            float d0 = fabsf(t0 - r.x);
            float d1 = fabsf(t1 - r.y);
            float d2 = fabsf(t2 - r.z);
            float d3 = fabsf(t3 - r.w);
            const float beta = 1.0f / 9.0f;
            const float hb   = 0.5f / 9.0f;
            regv += (d0 <= beta) ? 4.5f * d0 * d0 : d0 - hb;
            regv += (d1 <= beta) ? 4.5f * d1 * d1 : d1 - hb;
            regv += (d2 <= beta) ? 4.5f * d2 * d2 : d2 - hb;
            regv += (d3 <= beta) ? 4.5f * d3 * d3 : d3 - hb;
        }
    }

    // ---- wave (64) reduction, then block reduction, write partials ----
    for (int off = 32; off > 0; off >>= 1) {
        clsv += __shfl_down(clsv, off);
        regv += __shfl_down(regv, off);
        posn += __shfl_down(posn, off);
    }
    const int wid = tid >> 6;
    if ((tid & 63) == 0) {
        s_rc[wid] = clsv; s_rr[wid] = regv; s_rp[wid] = posn;
    }
    __syncthreads();
    if (tid == 0) {
        int idx = b * GX + blockIdx.x;
        ws_cls[idx] = s_rc[0] + s_rc[1] + s_rc[2] + s_rc[3];
        ws_reg[idx] = s_rr[0] + s_rr[1] + s_rr[2] + s_rr[3];
        ws_pos[idx] = s_rp[0] + s_rp[1] + s_rp[2] + s_rp[3];
    }
}

// ---------------------------------------------------------------------------
// Finalize: one wave per image reduces GX partials, normalizes, batch mean.
// ---------------------------------------------------------------------------
__global__ __launch_bounds__(512) void retina_final(
    const float* __restrict__ ws_cls,
    const float* __restrict__ ws_reg,
    const int*   __restrict__ ws_pos,
    float* __restrict__ out)
{
    __shared__ float s_c[B_N], s_r[B_N];
    const int tid  = threadIdx.x;
    const int img  = tid >> 6;          // 8 waves, one image each
    const int lane = tid & 63;

    float c = 0.0f, r = 0.0f;
    int   np = 0;
    for (int j = lane; j < GX; j += 64) {
        int idx = img * GX + j;
        c  += ws_cls[idx];
        r  += ws_reg[idx];
        np += ws_pos[idx];
    }
    for (int off = 32; off > 0; off >>= 1) {
        c  += __shfl_down(c, off);
        r  += __shfl_down(r, off);
        np += __shfl_down(np, off);
    }
    if (lane == 0) {
        float fnp = (float)np;
        s_c[img] = c / fmaxf(fnp, 1.0f);
        s_r[img] = (np > 0) ? r / fmaxf(fnp * 4.0f, 1.0f) : 0.0f;
    }
    __syncthreads();
    if (tid == 0) {
        float cc = 0.0f, rr = 0.0f;
        #pragma unroll
        for (int i = 0; i < B_N; ++i) { cc += s_c[i]; rr += s_r[i]; }
        out[0] = cc * (1.0f / (float)B_N);
        out[1] = rr * (1.0f / (float)B_N);
    }
}

extern "C" void kernel_launch(void* const* d_in, const int* in_sizes, int n_in,
                              void* d_out, int out_size, void* d_ws, size_t ws_size,
                              hipStream_t stream)
{
    const float* yt      = (const float*)d_in[0];  // y_true_tmp   (8,64,5)
    const float* ycls    = (const float*)d_in[1];  // y_classifs   (8,120000,1)
    const float* yreg    = (const float*)d_in[2];  // y_regressions(8,120000,4)
    const float* anchors = (const float*)d_in[3];  // anchors      (1,120000,4)

    float* ws_cls = (float*)d_ws;
    float* ws_reg = ws_cls + B_N * GX;
    int*   ws_pos = (int*)(ws_reg + B_N * GX);

    dim3 grid(GX, B_N);
    retina_main<<<grid, TPB, 0, stream>>>(yt, ycls, yreg, anchors,
                                          ws_cls, ws_reg, ws_pos);
    retina_final<<<1, 512, 0, stream>>>(ws_cls, ws_reg, ws_pos, (float*)d_out);
}

// Round 4
// 102.394 us; speedup vs baseline: 4.4884x; 1.0459x over previous
//
#include <hip/hip_runtime.h>

#define A_N 120000
#define B_N 8
#define M_N 64
#define APT 8                       // anchors per thread
#define TPB 256
#define GX  ((A_N + TPB*APT - 1) / (TPB*APT))   // 59 blocks in x

// ---------------------------------------------------------------------------
// Main kernel: each thread owns 8 anchors (strided by 256 for coalescing).
// IoU-max/argmax over the VALID GT prefix only (ngt is wave-uniform),
// division-free cross-mult compare, 8 independent dep chains per thread.
// Per-block partial sums written to ws (no atomics, no memset needed).
// ---------------------------------------------------------------------------
__global__ __launch_bounds__(TPB, 2) void retina_main(
    const float* __restrict__ yt,       // (B, M, 5)  cx,cy,w,h,label
    const float* __restrict__ ycls,     // (B, A, 1)
    const float* __restrict__ yreg,     // (B, A, 4)
    const float* __restrict__ anchors,  // (A, 4)     x1,y1,x2,y2
    float* __restrict__ ws_cls,         // [B*GX] partial cls sums
    float* __restrict__ ws_reg,         // [B*GX] partial reg sums
    int*   __restrict__ ws_pos)         // [B*GX] partial pos counts
{
    __shared__ float4 s_box[M_N];   // gt corners
    __shared__ float  s_area[M_N];  // gt area
    __shared__ float4 s_raw[M_N];   // raw cx,cy,w,h
    __shared__ float  s_lab[M_N];   // label
    __shared__ float  s_rc[4], s_rr[4];
    __shared__ int    s_rp[4];
    __shared__ int    s_ngt;

    const int b   = blockIdx.y;
    const int tid = threadIdx.x;
    const int a0  = blockIdx.x * (TPB * APT) + tid;   // + k*TPB

    if (tid < M_N) {                 // exactly wave 0, all 64 lanes active
        const float* g = yt + (b * M_N + tid) * 5;
        float cx = g[0], cy = g[1], w = g[2], h = g[3], lab = g[4];
        float x1 = cx - 0.5f * w, y1 = cy - 0.5f * h;
        float x2 = cx + 0.5f * w, y2 = cy + 0.5f * h;
        s_box[tid]  = make_float4(x1, y1, x2, y2);
        s_area[tid] = (x2 - x1) * (y2 - y1);
        s_raw[tid]  = make_float4(cx, cy, w, h);
        s_lab[tid]  = lab;
        // valid GTs are a prefix; count them (wave-uniform loop bound)
        unsigned long long mv = __ballot(lab != -1.0f);
        if (tid == 0) s_ngt = (int)__popcll(mv);
    }
    __syncthreads();
    const int ngt = s_ngt;           // >= 1 always

    // ---- per-anchor state (static indices -> registers) ----
    float ax1[APT], ay1[APT], ax2[APT], ay2[APT], sa[APT], pp[APT];
    float bi[APT], bd[APT];
    int   ba[APT];

    #pragma unroll
    for (int k = 0; k < APT; ++k) {
        int a  = a0 + k * TPB;
        int ac = (a < A_N) ? a : (A_N - 1);         // clamp, mask at tail
        float4 an = *reinterpret_cast<const float4*>(anchors + (size_t)ac * 4);
        ax1[k] = an.x; ay1[k] = an.y; ax2[k] = an.z; ay2[k] = an.w;
        sa[k]  = (an.z - an.x) * (an.w - an.y);     // anchor area
        pp[k]  = ycls[(size_t)b * A_N + ac];        // prefetch p
        bi[k] = -1.0f; bd[k] = 1.0f; ba[k] = 0;
    }

    // ---- inner loop over valid GT prefix ----
    #pragma unroll 4
    for (int g = 0; g < ngt; ++g) {
        const float4 gb = s_box[g];
        const float  ga = s_area[g];
        #pragma unroll
        for (int k = 0; k < APT; ++k) {
            float w = fminf(ax2[k], gb.z) - fmaxf(ax1[k], gb.x);
            float h = fminf(ay2[k], gb.w) - fmaxf(ay1[k], gb.y);
            float inter = fmaxf(w, 0.0f) * fmaxf(h, 0.0f);
            float denom = (sa[k] + ga) - inter;     // > 0 always
            // inter/denom > bi/bd  <=>  inter*bd > bi*denom ; strict > = first-max
            bool better = inter * bd[k] > bi[k] * denom;
            bi[k] = better ? inter : bi[k];
            bd[k] = better ? denom : bd[k];
            ba[k] = better ? g     : ba[k];
        }
    }

    // ---- per-anchor tail: focal cls + smooth-L1 reg ----
    float clsv = 0.0f, regv = 0.0f;
    int   posn = 0;
    #pragma unroll
    for (int k = 0; k < APT; ++k) {
        int a = a0 + k * TPB;
        if (a >= A_N) continue;
        const bool pos = (bi[k] >= 0.5f * bd[k]);
        const bool neg = (bi[k] <  0.4f * bd[k]);
        posn += pos ? 1 : 0;
        const float p = pp[k];

        float target;
        if (pos) {
            int alab = (int)s_lab[ba[k]];           // arg valid when pos
            target = (alab == 0) ? 1.0f : 0.0f;
        } else {
            target = neg ? 0.0f : -1.0f;
        }
        if (target == 1.0f) {
            float fw = 1.0f - p;
            clsv += 0.25f * fw * fw * (-logf(p));
        } else if (target == 0.0f) {
            clsv += 0.75f * p * p * (-logf(1.0f - p));
        }

        if (pos) {
            const float aw  = ax2[k] - ax1[k];
            const float ah  = ay2[k] - ay1[k];
            const float acx = ax1[k] + 0.5f * aw;
            const float acy = ay1[k] + 0.5f * ah;
            const float4 ag = s_raw[ba[k]];
            const float4 r  = *reinterpret_cast<const float4*>(yreg + ((size_t)b * A_N + a) * 4);
            float gw = fmaxf(ag.z, 1.0f);
            float gh = fmaxf(ag.w, 1.0f);
            float t0 = ((ag.x - acx) / aw) / 0.1f;
            float t1 = ((ag.y - acy) / ah) / 0.1f;
            float t2 = logf(gw / aw) / 0.2f;
            float t3 = logf(gh / ah) / 0.2f;
            float d0 = fabsf(t0 - r.x);
            float d1 = fabsf(t1 - r.y);
            float d2 = fabsf(t2 - r.z);
            float d3 = fabsf(t3 - r.w);
            const float beta = 1.0f / 9.0f;
            const float hb   = 0.5f / 9.0f;
            regv += (d0 <= beta) ? 4.5f * d0 * d0 : d0 - hb;
            regv += (d1 <= beta) ? 4.5f * d1 * d1 : d1 - hb;
            regv += (d2 <= beta) ? 4.5f * d2 * d2 : d2 - hb;
            regv += (d3 <= beta) ? 4.5f * d3 * d3 : d3 - hb;
        }
    }

    // ---- wave (64) reduction, then block reduction, write partials ----
    for (int off = 32; off > 0; off >>= 1) {
        clsv += __shfl_down(clsv, off);
        regv += __shfl_down(regv, off);
        posn += __shfl_down(posn, off);
    }
    const int wid = tid >> 6;
    if ((tid & 63) == 0) {
        s_rc[wid] = clsv; s_rr[wid] = regv; s_rp[wid] = posn;
    }
    __syncthreads();
    if (tid == 0) {
        int idx = b * GX + blockIdx.x;
        ws_cls[idx] = s_rc[0] + s_rc[1] + s_rc[2] + s_rc[3];
        ws_reg[idx] = s_rr[0] + s_rr[1] + s_rr[2] + s_rr[3];
        ws_pos[idx] = s_rp[0] + s_rp[1] + s_rp[2] + s_rp[3];
    }
}

// ---------------------------------------------------------------------------
// Finalize: one wave per image reduces GX partials, normalizes, batch mean.
// ---------------------------------------------------------------------------
__global__ __launch_bounds__(512) void retina_final(
    const float* __restrict__ ws_cls,
    const float* __restrict__ ws_reg,
    const int*   __restrict__ ws_pos,
    float* __restrict__ out)
{
    __shared__ float s_c[B_N], s_r[B_N];
    const int tid  = threadIdx.x;
    const int img  = tid >> 6;          // 8 waves, one image each
    const int lane = tid & 63;

    float c = 0.0f, r = 0.0f;
    int   np = 0;
    for (int j = lane; j < GX; j += 64) {
        int idx = img * GX + j;
        c  += ws_cls[idx];
        r  += ws_reg[idx];
        np += ws_pos[idx];
    }
    for (int off = 32; off > 0; off >>= 1) {
        c  += __shfl_down(c, off);
        r  += __shfl_down(r, off);
        np += __shfl_down(np, off);
    }
    if (lane == 0) {
        float fnp = (float)np;
        s_c[img] = c / fmaxf(fnp, 1.0f);
        s_r[img] = (np > 0) ? r / fmaxf(fnp * 4.0f, 1.0f) : 0.0f;
    }
    __syncthreads();
    if (tid == 0) {
        float cc = 0.0f, rr = 0.0f;
        #pragma unroll
        for (int i = 0; i < B_N; ++i) { cc += s_c[i]; rr += s_r[i]; }
        out[0] = cc * (1.0f / (float)B_N);
        out[1] = rr * (1.0f / (float)B_N);
    }
}

extern "C" void kernel_launch(void* const* d_in, const int* in_sizes, int n_in,
                              void* d_out, int out_size, void* d_ws, size_t ws_size,
                              hipStream_t stream)
{
    const float* yt      = (const float*)d_in[0];  // y_true_tmp   (8,64,5)
    const float* ycls    = (const float*)d_in[1];  // y_classifs   (8,120000,1)
    const float* yreg    = (const float*)d_in[2];  // y_regressions(8,120000,4)
    const float* anchors = (const float*)d_in[3];  // anchors      (1,120000,4)

    float* ws_cls = (float*)d_ws;
    float* ws_reg = ws_cls + B_N * GX;
    int*   ws_pos = (int*)(ws_reg + B_N * GX);

    dim3 grid(GX, B_N);
    retina_main<<<grid, TPB, 0, stream>>>(yt, ycls, yreg, anchors,
                                          ws_cls, ws_reg, ws_pos);
    retina_final<<<1, 512, 0, stream>>>(ws_cls, ws_reg, ws_pos, (float*)d_out);
}